// Round 4
// baseline (236.753 us; speedup 1.0000x reference)
//
#include <hip/hip_runtime.h>
#include <math.h>

// Problem: ProcessFeatures_83296595738632
// corr[bs,bg,i] = sum_{h,j,k} sat[bs,h,(i+j)%64,k] * grd[bg,h,j,15-k]
// orien = argmax_i corr (first-max); dot with cyclic shift orien, /||sat||
// distance[bg,bs] = 2-2*dot; out: sat | grd | distance | orien(float)
//
// R4: lane = shift i, wave = h. sat tile in LDS (swizzled, 4x ds_read_b128/j,
// 2-way = free). grd rows WAVE-UNIFORM via s_load -> SGPR operands feeding
// v_fmac directly: zero DS traffic for grd, 128 pure FMAs per j.

#define BS   96
#define H    4
#define W    64
#define C    16
#define BG   96
#define NB   8
#define NTH  256
#define HWC  (H*W*C)

#define SAT_ELEMS (BS*H*W*C)          // 393216
#define OUT_DIST  (2*SAT_ELEMS)       // 786432
#define OUT_ORIEN (OUT_DIST + BS*BG)  // 795648

// satL swizzle: chunk c4 of row hw at slot (c4 + (hw>>1)) & 3
__device__ __forceinline__ int satIdx(int hw, int c4) {
    return hw * 16 + 4 * ((c4 + (hw >> 1)) & 3);
}

__global__ __launch_bounds__(NTH)
void pf_fused_kernel(const float* __restrict__ sat,
                     const float* __restrict__ grd,
                     float* __restrict__ out)
{
    __shared__ float satL[H * W * C];     // 16 KB
    __shared__ float partL[NB * 4 * W];   // 8 KB, [b][wv][lane] lane-stride-1
    __shared__ float sumL[4];
    __shared__ float dotP[NB * 4];
    __shared__ int   orienL[NB];

    const int bs   = blockIdx.y;
    const int bg0  = blockIdx.x * NB;
    const int tid  = threadIdx.x;
    const int wv   = tid >> 6;
    const int lane = tid & 63;

    // ---- stage sat[bs] into swizzled LDS ----
    {
        const float4* satB = (const float4*)(sat + (size_t)bs * HWC);
        #pragma unroll
        for (int x = tid; x < HWC / 4; x += NTH) {
            int hw = x >> 2, c4 = x & 3;
            *(float4*)&satL[satIdx(hw, c4)] = satB[x];
        }
    }
    __syncthreads();

    // ---- per-h squared sums (for the norm) ----
    {
        float s = 0.f;
        const int hw = wv * W + lane;
        #pragma unroll
        for (int c4 = 0; c4 < 4; ++c4) {
            float4 v = *(const float4*)&satL[satIdx(hw, c4)];
            s = fmaf(v.x, v.x, fmaf(v.y, v.y, fmaf(v.z, v.z, fmaf(v.w, v.w, s))));
        }
        #pragma unroll
        for (int off = 32; off; off >>= 1) s += __shfl_xor(s, off);
        if (lane == 0) sumL[wv] = s;
    }

    // ---- corr: lane = shift i, wave = h ----
    // grd addresses wave-uniform -> scalarize (s_load), SGPR operands in FMAs.
    const int gofs = __builtin_amdgcn_readfirstlane((bg0 * H + wv) * W * C);
    const float* __restrict__ grdU = grd + gofs;

    float acc[NB];
    #pragma unroll
    for (int b = 0; b < NB; ++b) acc[b] = 0.f;

    #pragma unroll 2
    for (int j = 0; j < W; ++j) {
        const int r = (lane + j) & 63;
        const int hw = wv * W + r;
        float4 s0 = *(const float4*)&satL[satIdx(hw, 0)];
        float4 s1 = *(const float4*)&satL[satIdx(hw, 1)];
        float4 s2 = *(const float4*)&satL[satIdx(hw, 2)];
        float4 s3 = *(const float4*)&satL[satIdx(hw, 3)];

        #pragma unroll
        for (int b = 0; b < NB; ++b) {
            const float* __restrict__ g = grdU + b * HWC + j * C;
            // reversed-c pairing; 16 FMAs chained into acc[b] (8 indep chains across b)
            float a = acc[b];
            a = fmaf(s0.x, g[15], a); a = fmaf(s0.y, g[14], a);
            a = fmaf(s0.z, g[13], a); a = fmaf(s0.w, g[12], a);
            a = fmaf(s1.x, g[11], a); a = fmaf(s1.y, g[10], a);
            a = fmaf(s1.z, g[ 9], a); a = fmaf(s1.w, g[ 8], a);
            a = fmaf(s2.x, g[ 7], a); a = fmaf(s2.y, g[ 6], a);
            a = fmaf(s2.z, g[ 5], a); a = fmaf(s2.w, g[ 4], a);
            a = fmaf(s3.x, g[ 3], a); a = fmaf(s3.y, g[ 2], a);
            a = fmaf(s3.z, g[ 1], a); a = fmaf(s3.w, g[ 0], a);
            acc[b] = a;
        }
    }

    #pragma unroll
    for (int b = 0; b < NB; ++b) partL[(b * 4 + wv) * W + lane] = acc[b];
    __syncthreads();

    // ---- argmax per bg (first-max tie-break) ----
    for (int b = wv; b < NB; b += 4) {
        float v = (partL[(b*4+0)*W + lane] + partL[(b*4+1)*W + lane])
                + (partL[(b*4+2)*W + lane] + partL[(b*4+3)*W + lane]);
        int idx = lane;
        #pragma unroll
        for (int off = 32; off; off >>= 1) {
            float ov = __shfl_xor(v, off);
            int   oi = __shfl_xor(idx, off);
            if (ov > v || (ov == v && oi < idx)) { v = ov; idx = oi; }
        }
        if (lane == 0) {
            orienL[b] = idx;
            out[OUT_ORIEN + bs * BG + (bg0 + b)] = (float)idx;
        }
    }
    __syncthreads();

    const float nrm = sqrtf(sumL[0] + sumL[1] + sumL[2] + sumL[3] + 1e-8f);

    // ---- dot phase: wave = h, lane = j ----
    {
        float dp[NB];
        #pragma unroll
        for (int b = 0; b < NB; ++b) {
            const int row = (lane + orienL[b]) & 63;
            const float* gRow = grd + (((size_t)(bg0 + b) * H + wv) * W + lane) * C;
            float s = 0.f;
            #pragma unroll
            for (int c4 = 0; c4 < 4; ++c4) {
                float4 sv = *(const float4*)&satL[satIdx(wv * W + row, c4)];
                float4 gv = *(const float4*)(gRow + 4 * c4);
                s = fmaf(sv.x, gv.x, fmaf(sv.y, gv.y, fmaf(sv.z, gv.z, fmaf(sv.w, gv.w, s))));
            }
            dp[b] = s;
        }
        #pragma unroll
        for (int b = 0; b < NB; ++b) {
            float s = dp[b];
            #pragma unroll
            for (int off = 32; off; off >>= 1) s += __shfl_xor(s, off);
            if (lane == 0) dotP[b * 4 + wv] = s;
        }
    }
    __syncthreads();

    if (tid < NB) {
        float d = ((dotP[tid*4+0] + dotP[tid*4+1]) + (dotP[tid*4+2] + dotP[tid*4+3])) / nrm;
        out[OUT_DIST + (size_t)(bg0 + tid) * BS + bs] = 2.f - 2.f * d;
    }
}

extern "C" void kernel_launch(void* const* d_in, const int* in_sizes, int n_in,
                              void* d_out, int out_size, void* d_ws, size_t ws_size,
                              hipStream_t stream) {
    const float* sat = (const float*)d_in[0];
    const float* grd = (const float*)d_in[1];
    float* out = (float*)d_out;

    hipMemcpyAsync(out,             sat, (size_t)SAT_ELEMS * sizeof(float),
                   hipMemcpyDeviceToDevice, stream);
    hipMemcpyAsync(out + SAT_ELEMS, grd, (size_t)SAT_ELEMS * sizeof(float),
                   hipMemcpyDeviceToDevice, stream);

    dim3 grid(BG / NB, BS);   // (12, 96)
    pf_fused_kernel<<<grid, NTH, 0, stream>>>(sat, grd, out);
}